// Round 5
// baseline (465.221 us; speedup 1.0000x reference)
//
#include <hip/hip_runtime.h>

// DEQ fused kernel, round 5: BARRIER-FREE, 1 wave per block.
//
// out = relu^{(30)}(z Wz^T + inj) @ Wd^T + bd,  inj = x Ux^T + b
//
// Each 64-thread block is ONE wave owning 16 batch rows and the FULL hidden
// dim (n = 128):
//   - Wz register-resident as 8x4 A-fragments (128 VGPRs, iteration-invariant)
//   - D[n][m] = sum_k Wz[n][k] Z^T[k][m]; D's register axis = n = next
//     iteration's k axis -> packed ds_write_b64 stores / ds_read_b128 loads
//     into a wave-PRIVATE 4 KB LDS tile. Same-wave DS ordering (lgkmcnt)
//     replaces __syncthreads: the kernel has NO barriers at all.
//   - 8 independent MFMA chains of depth 4 per iteration (the r1/r3 ILP
//     shape; r4 showed depth-8/2-chain stalls the matrix pipe).
//   - __launch_bounds__(64,2): 2 waves/SIMD -> 256-reg budget, total need
//     ~215 regs -> no spill (r2's failure was a 4-wave 256-thread block).
//
// LDS: row-major z[m][k], 16 rows x 128 bf16 (256 B stride), 16B-chunk XOR
// swizzle c' = c ^ (m&7): b128 reads conflict-free, b64 writes 2-way (free).

typedef __attribute__((ext_vector_type(8))) __bf16 bf16x8;
typedef __attribute__((ext_vector_type(4))) __bf16 bf16x4;
typedef __attribute__((ext_vector_type(4))) float  floatx4;

#define MFMA16(a, b, c) __builtin_amdgcn_mfma_f32_16x16x32_bf16((a), (b), (c), 0, 0, 0)

static constexpr int kBsz  = 262144;
static constexpr int kRows = 16;   // batch rows per wave(=block)

__device__ __forceinline__ bf16x8 cvt_bf16x8(float4 a, float4 b) {
  bf16x8 r;
  r[0] = (__bf16)a.x; r[1] = (__bf16)a.y; r[2] = (__bf16)a.z; r[3] = (__bf16)a.w;
  r[4] = (__bf16)b.x; r[5] = (__bf16)b.y; r[6] = (__bf16)b.z; r[7] = (__bf16)b.w;
  return r;
}

// swizzled bf16-index of (row m, 16B-chunk c, bf16 offset within chunk)
__device__ __forceinline__ int zidx(int m, int c, int off) {
  return m * 128 + 8 * (c ^ (m & 7)) + off;
}

__global__ void __launch_bounds__(64, 2) deq_fused(
    const float* __restrict__ x,    // [B,64]
    const float* __restrict__ Wz,   // [128,128]
    const float* __restrict__ Ux,   // [128,64]
    const float* __restrict__ bvec, // [128]
    const float* __restrict__ Wd,   // [64,128]
    const float* __restrict__ bd,   // [64]
    const int*  __restrict__ n_iters_p,
    float* __restrict__ out)        // [B,64]
{
  __shared__ __align__(16) __bf16 zl[kRows * 128];  // 4 KB, wave-private

  const int lane = threadIdx.x & 63;
  const int l15  = lane & 15;
  const int quad = lane >> 4;  // 0..3
  const int grow = blockIdx.x * kRows + l15;  // this lane's batch row (m)
  const int iters = *n_iters_p;

  // ---- inj in C/D layout: reg i -> n = 16nt + 4quad + i, col(l15) -> m ----
  floatx4 inj[8];
#pragma unroll
  for (int nt = 0; nt < 8; ++nt) {
    const float4 bv = *(const float4*)(bvec + 16 * nt + 4 * quad);
    floatx4 v = {bv.x, bv.y, bv.z, bv.w};
    inj[nt] = v;
  }
  {
    // encoder: inj += Ux @ x^T  (A = Ux, K = 64 -> 2 k-steps)
#pragma unroll
    for (int ks = 0; ks < 2; ++ks) {
      const float4* px = (const float4*)(x + (size_t)grow * 64 + 32 * ks + 8 * quad);
      const bf16x8 bx = cvt_bf16x8(px[0], px[1]);
#pragma unroll
      for (int nt = 0; nt < 8; ++nt) {
        const int n = 16 * nt + l15;
        const float4* p = (const float4*)(Ux + n * 64 + 32 * ks + 8 * quad);
        inj[nt] = MFMA16(cvt_bf16x8(p[0], p[1]), bx, inj[nt]);
      }
    }
  }

  // ---- Wz as A-fragments (iteration-invariant, 128 VGPRs) ----
  // A[n][k]: n = 16*nt + l15, k = 32*ks + 8*quad + j
  bf16x8 awz[8][4];
#pragma unroll
  for (int nt = 0; nt < 8; ++nt) {
    const int n = 16 * nt + l15;
#pragma unroll
    for (int ks = 0; ks < 4; ++ks) {
      const float4* p = (const float4*)(Wz + n * 128 + 32 * ks + 8 * quad);
      awz[nt][ks] = cvt_bf16x8(p[0], p[1]);
    }
  }

  // ---- z1 = relu(inj) (z0 = 0): n = 16nt+4q -> chunk 2nt+(q>>1), off 4(q&1)
#pragma unroll
  for (int nt = 0; nt < 8; ++nt) {
    bf16x4 z4;
#pragma unroll
    for (int i = 0; i < 4; ++i) z4[i] = (__bf16)fmaxf(inj[nt][i], 0.0f);
    *(bf16x4*)&zl[zidx(l15, 2 * nt + (quad >> 1), 4 * (quad & 1))] = z4;
  }

  // ---- fixed-point loop: NO barriers; same-wave lgkm ordering is enough ----
#pragma unroll 1
  for (int t = 0; t < iters - 1; ++t) {
    // B-frags: B[k][m], k = 32ks + 8q + j -> chunk 4ks+q at row l15 (b128)
    bf16x8 bz[4];
#pragma unroll
    for (int ks = 0; ks < 4; ++ks)
      bz[ks] = *(const bf16x8*)&zl[zidx(l15, 4 * ks + quad, 0)];
    floatx4 acc[8];
#pragma unroll
    for (int nt = 0; nt < 8; ++nt) {
      acc[nt] = MFMA16(awz[nt][0], bz[0], inj[nt]);
#pragma unroll
      for (int ks = 1; ks < 4; ++ks)
        acc[nt] = MFMA16(awz[nt][ks], bz[ks], acc[nt]);
    }
#pragma unroll
    for (int nt = 0; nt < 8; ++nt) {
      bf16x4 z4;
#pragma unroll
      for (int i = 0; i < 4; ++i) z4[i] = (__bf16)fmaxf(acc[nt][i], 0.0f);
      *(bf16x4*)&zl[zidx(l15, 2 * nt + (quad >> 1), 4 * (quad & 1))] = z4;
    }
  }

  // ---- decoder: D[o][m] = sum_k Wd[o][k] Z^T[k][m] + bd ----
  {
    bf16x8 bz[4];
#pragma unroll
    for (int ks = 0; ks < 4; ++ks)
      bz[ks] = *(const bf16x8*)&zl[zidx(l15, 4 * ks + quad, 0)];
#pragma unroll
    for (int ot = 0; ot < 4; ++ot) {
      const int o = 16 * ot + l15;
      const float4 bv = *(const float4*)(bd + 16 * ot + 4 * quad);
      floatx4 acc = {bv.x, bv.y, bv.z, bv.w};
#pragma unroll
      for (int ks = 0; ks < 4; ++ks) {
        const float4* p = (const float4*)(Wd + o * 128 + 32 * ks + 8 * quad);
        acc = MFMA16(cvt_bf16x8(p[0], p[1]), bz[ks], acc);
      }
      // reg i -> o = 16ot + 4q + i (consecutive), row = grow
      float4 ov;
      ov.x = acc[0]; ov.y = acc[1]; ov.z = acc[2]; ov.w = acc[3];
      *(float4*)(out + (size_t)grow * 64 + 16 * ot + 4 * quad) = ov;
    }
  }
}

extern "C" void kernel_launch(void* const* d_in, const int* in_sizes, int n_in,
                              void* d_out, int out_size, void* d_ws, size_t ws_size,
                              hipStream_t stream) {
  const float* x  = (const float*)d_in[0];
  const float* Wz = (const float*)d_in[1];
  const float* Ux = (const float*)d_in[2];
  const float* b  = (const float*)d_in[3];
  const float* Wd = (const float*)d_in[4];
  const float* bd = (const float*)d_in[5];
  const int* n_it = (const int*)d_in[6];
  float* out = (float*)d_out;
  (void)in_sizes; (void)n_in; (void)d_ws; (void)ws_size; (void)out_size;

  dim3 grid(kBsz / kRows);  // 16384 one-wave blocks
  deq_fused<<<grid, 64, 0, stream>>>(x, Wz, Ux, b, Wd, bd, n_it, out);
}